// Round 14
// baseline (200.802 us; speedup 1.0000x reference)
//
#include <hip/hip_runtime.h>
#include <math.h>

#define XD 48
#define YD 48
#define ZD 48
#define CD 64
#define NGT 10
#define NB 2
#define KP 128
#define MVOX (XD*YD*ZD)   // 110592
#define ANCH 12.0f
#define BLK_PER_BATCH 432 // MVOX/256

// topk: single-level log-distance histogram select
#define NBIN 2048
#define CANDCAP 4096

typedef float v2f __attribute__((ext_vector_type(2)));

// bin' (inverted: larger bin' = larger pj), monotone in pj bits. Exact superset filter.
__device__ __forceinline__ unsigned pjbin(unsigned pbits) {
  unsigned d = 0x3F800000u - pbits;         // ULP-distance from 1.0 (pj in [0,1])
  if (d == 0u) return 2047u;
  int msb = 31 - __clz(d);
  unsigned frac = (msb >= 6) ? ((d >> (msb - 6)) & 63u) : ((d << (6 - msb)) & 63u);
  unsigned bin = ((unsigned)msb << 6) | frac; // monotone increasing in d, < 1920
  return 2047u - bin;                         // invert: suffix-scan finds top
}

// ---------------- conv: direct, x-strips of 6, shfl halos, packed f32 FMA ----------------
// pred4 layout (z-major): pred4[((cg*NB+b)*7+o)*MVOX + z*(YD*XD) + y*XD + x]
template<int CPG>
__global__ __launch_bounds__(192) void conv_kernel(const float* __restrict__ feat_zyx,
                                                   const float* __restrict__ Wt,
                                                   float* __restrict__ pred4,
                                                   unsigned* __restrict__ zeroBuf,
                                                   int zeroN) {
  const int t = threadIdx.x;
  const int q = t & 7;                 // x-segment 0..7 (x0 = 6q)
  const int y = blockIdx.y*24 + (t >> 3);
  const int z = blockIdx.x;
  const int cg = blockIdx.z >> 1;      // NB == 2
  const int b  = blockIdx.z & 1;
  const int c0 = cg * CPG;
  const int x0 = q * 6;

  // fused zeroing of topk histogram (conv completes before loss)
  if (blockIdx.x == 0 && blockIdx.y == 0 && blockIdx.z == 0)
    for (int i = t; i < zeroN; i += 192) zeroBuf[i] = 0u;

  v2f acc[7][3];
  #pragma unroll
  for (int o = 0; o < 7; ++o)
    #pragma unroll
    for (int j = 0; j < 3; ++j) acc[o][j] = (v2f){0.f, 0.f};

  const float* fb = feat_zyx + ((size_t)b*CD + c0) * MVOX;
  #pragma unroll 2
  for (int cc = 0; cc < CPG; ++cc) {
    const float* fc = fb + (size_t)cc * MVOX;
    const float* Wc = Wt + (c0 + cc) * 27;
    #pragma unroll
    for (int dz = -1; dz <= 1; ++dz) {
      const int zz = z + dz;
      if (zz < 0 || zz >= ZD) continue;      // wave-uniform (z per block)
      #pragma unroll
      for (int dy = -1; dy <= 1; ++dy) {
        const int yy = y + dy;
        const bool vrow = (yy >= 0 && yy < YD);
        const float* rp = fc + (zz*YD + (vrow ? yy : 0))*XD + x0; // 8B-aligned, in-bounds
        float2 p01 = *(const float2*)(rp);
        float2 p23 = *(const float2*)(rp + 2);
        float2 p45 = *(const float2*)(rp + 4);
        const float e1 = vrow ? p01.x : 0.f, e2 = vrow ? p01.y : 0.f;
        const float e3 = vrow ? p23.x : 0.f, e4 = vrow ? p23.y : 0.f;
        const float e5 = vrow ? p45.x : 0.f, e6 = vrow ? p45.y : 0.f;
        const float eL = __shfl_up(e6, 1);   // lane q-1 (same y-group), masked at q==0
        const float eR = __shfl_down(e1, 1); // lane q+1, masked at q==7
        const float e0 = (q == 0) ? 0.f : eL;
        const float e7 = (q == 7) ? 0.f : eR;
        const v2f A0 = {e0, e1}, A1 = {e2, e3}, A2 = {e4, e5};
        const v2f B0 = {e1, e2}, B1 = {e3, e4}, B2 = {e5, e6};
        const v2f C2 = {e6, e7};
        const int kb = (dy + 1)*3 + (dz + 1); // W[o][c][kt][dy+1][dz+1]
        #pragma unroll
        for (int o = 0; o < 7; ++o) {
          const float w0 = Wc[o*(CD*27) + kb];
          const float w1 = Wc[o*(CD*27) + 9 + kb];
          const float w2 = Wc[o*(CD*27) + 18 + kb];
          const v2f w0v = {w0, w0}, w1v = {w1, w1}, w2v = {w2, w2};
          acc[o][0] = __builtin_elementwise_fma(A0, w0v, acc[o][0]);
          acc[o][0] = __builtin_elementwise_fma(B0, w1v, acc[o][0]);
          acc[o][0] = __builtin_elementwise_fma(A1, w2v, acc[o][0]);
          acc[o][1] = __builtin_elementwise_fma(A1, w0v, acc[o][1]);
          acc[o][1] = __builtin_elementwise_fma(B1, w1v, acc[o][1]);
          acc[o][1] = __builtin_elementwise_fma(A2, w2v, acc[o][1]);
          acc[o][2] = __builtin_elementwise_fma(A2, w0v, acc[o][2]);
          acc[o][2] = __builtin_elementwise_fma(B2, w1v, acc[o][2]);
          acc[o][2] = __builtin_elementwise_fma(C2, w2v, acc[o][2]);
        }
      }
    }
  }
  float* pb = pred4 + ((size_t)(cg*NB + b)*7)*MVOX + (size_t)z*(YD*XD) + y*XD + x0;
  #pragma unroll
  for (int o = 0; o < 7; ++o) {
    *(v2f*)(pb + (size_t)o*MVOX)     = acc[o][0];
    *(v2f*)(pb + (size_t)o*MVOX + 2) = acc[o][1];
    *(v2f*)(pb + (size_t)o*MVOX + 4) = acc[o][2];
  }
}

// ---------------- loss + fused log-bin histogram (z-major iteration) ----------------
template<int GG>
__global__ __launch_bounds__(256) void loss_kernel(const float* __restrict__ pred4,
                                                   const float* __restrict__ cbias,
                                                   const float* __restrict__ lrt,
                                                   const float* __restrict__ scores,
                                                   float* __restrict__ pobj,
                                                   float* __restrict__ partials,
                                                   unsigned* __restrict__ hist1) {
  const int blk = blockIdx.x;
  const int b = blk / BLK_PER_BATCH;
  const int w = (blk % BLK_PER_BATCH) * 256 + threadIdx.x; // z-major linear
  const int z = w / (YD*XD);
  const int rem = w % (YD*XD);
  const int y = rem / XD, x = rem % XD;

  __shared__ float gp[NGT][10];
  __shared__ unsigned lh[NBIN];
  for (int i = threadIdx.x; i < NBIN; i += 256) lh[i] = 0;
  if (threadIdx.x < NGT) {
    const float* g = lrt + (b*NGT + threadIdx.x)*19;
    float l0 = g[0], l1 = g[1], l2 = g[2];
    gp[threadIdx.x][0] = g[6]; gp[threadIdx.x][1] = g[10]; gp[threadIdx.x][2] = g[14];
    gp[threadIdx.x][3] = l0*0.5f + 1e-5f;
    gp[threadIdx.x][4] = l1*0.5f + 1e-5f;
    gp[threadIdx.x][5] = l2*0.5f + 1e-5f;
    gp[threadIdx.x][6] = logf(l0 / ANCH);
    gp[threadIdx.x][7] = logf(l1 / ANCH);
    gp[threadIdx.x][8] = logf(l2 / ANCH);
    gp[threadIdx.x][9] = scores[b*NGT + threadIdx.x];
  }
  __syncthreads();

  float pv[7];
  #pragma unroll
  for (int k = 0; k < 7; ++k) pv[k] = cbias[k];
  #pragma unroll
  for (int g = 0; g < GG; ++g) {
    const float* p = pred4 + ((size_t)(g*NB + b)*7)*MVOX + w;
    #pragma unroll
    for (int k = 0; k < 7; ++k) pv[k] += p[(size_t)k*MVOX];
  }

  const float l = pv[0];
  const float pj = 1.f / (1.f + expf(-l));
  pobj[(size_t)b*MVOX + x*(YD*ZD) + y*ZD + z] = pj; // x-major output order
  atomicAdd(&lh[pjbin(__float_as_uint(pj))], 1u);

  const float fx = (float)x, fy = (float)y, fz = (float)z;
  float cum = 0.f, sneg = 0.f;
  float a[6] = {0.f,0.f,0.f,0.f,0.f,0.f};
  #pragma unroll
  for (int n = 0; n < NGT; ++n) {
    float d0 = gp[n][0] - fx, d1 = gp[n][1] - fy, d2 = gp[n][2] - fz;
    float od = fmaxf(fmaxf(fabsf(d0)/gp[n][3],
                           fabsf(d1)/gp[n][4]),
                           fabsf(d2)/gp[n][5]);
    float sc = gp[n][9];
    float mp = (od < 0.5f) ? sc : 0.f;
    float mn = (od < 0.8f) ? sc : 0.f;
    float prev = (cum >= 0.5f) ? 1.f : 0.f;
    float ctb = mp * (1.f - prev);
    a[0] += ctb * (d0 / ANCH);
    a[1] += ctb * (d1 / ANCH);
    a[2] += ctb * (d2 / ANCH);
    a[3] += ctb * gp[n][6];
    a[4] += ctb * gp[n][7];
    a[5] += ctb * gp[n][8];
    cum += mp; sneg += mn;
  }
  const float pos = (cum  >= 0.5f) ? 1.f : 0.f;
  const float neg = 1.f - ((sneg >= 0.5f) ? 1.f : 0.f);
  const float bce = fmaxf(l, 0.f) - l*pos + log1pf(expf(-fabsf(l)));
  float sl = 0.f;
  #pragma unroll
  for (int c = 0; c < 6; ++c) {
    float dd = pos * pv[1+c] - pos * a[c];
    float ad = fabsf(dd);
    sl += (ad < (1.f/9.f)) ? dd*dd*4.5f : (ad - (1.f/18.f));
  }

  float vals5[5] = {bce*pos, bce*neg, pos, neg, sl};
  __shared__ float red[4][5];
  const int lane = threadIdx.x & 63, wid = threadIdx.x >> 6;
  #pragma unroll
  for (int k = 0; k < 5; ++k)
    for (int off = 32; off; off >>= 1)
      vals5[k] += __shfl_down(vals5[k], off);
  if (lane == 0) {
    #pragma unroll
    for (int k = 0; k < 5; ++k) red[wid][k] = vals5[k];
  }
  __syncthreads();
  if (threadIdx.x == 0) {
    #pragma unroll
    for (int k = 0; k < 5; ++k)
      partials[blk*5 + k] = red[0][k] + red[1][k] + red[2][k] + red[3][k];
  }
  for (int i = threadIdx.x; i < NBIN; i += 256) {
    unsigned h = lh[i];
    if (h) atomicAdd(&hist1[b*NBIN + i], h);
  }
}

// suffix scan of ghist into sA (uses sB as ping-pong), stride = blockDim.x. Result in sA.
__device__ __forceinline__ void suffix2048(const unsigned* __restrict__ ghist,
                                           unsigned* sA, unsigned* sB) {
  const int nt = blockDim.x;
  for (int i = threadIdx.x; i < NBIN; i += nt) sA[i] = ghist[i];
  __syncthreads();
  unsigned* src = sA; unsigned* dst = sB;
  for (int off = 1; off < NBIN; off <<= 1) {
    for (int i = threadIdx.x; i < NBIN; i += nt)
      dst[i] = src[i] + ((i + off < NBIN) ? src[i + off] : 0u);
    __syncthreads();
    unsigned* t = src; src = dst; dst = t;
  }
  if (src != sA) {
    for (int i = threadIdx.x; i < NBIN; i += nt) sA[i] = src[i];
    __syncthreads();
  }
}

// ---------------- fused: threshold + collect + sort + NMS + outputs (+ loss finalize) ----------------
__device__ inline float iou2(const float* A, const float* Bb) {
  float lo1 = fmaxf(A[0], Bb[0]), lo2 = fmaxf(A[1], Bb[1]);
  float hi1 = fminf(A[2], Bb[2]), hi2 = fminf(A[3], Bb[3]);
  float inter = fmaxf(hi1 - lo1, 0.f) * fmaxf(hi2 - lo2, 0.f);
  float aA = (A[2]-A[0])*(A[3]-A[1]);
  float aB = (Bb[2]-Bb[0])*(Bb[3]-Bb[1]);
  return inter / (aA + aB - inter + 1e-9f);
}

__global__ __launch_bounds__(1024) void final_all(const float* __restrict__ pobj,
                                                  const unsigned* __restrict__ hist1,
                                                  const float* __restrict__ pred4,
                                                  const float* __restrict__ cbias,
                                                  int G,
                                                  const float* __restrict__ lrt,
                                                  const float* __restrict__ scores,
                                                  const float* __restrict__ partials,
                                                  float* __restrict__ out_loss,
                                                  float* __restrict__ out_boxes,
                                                  float* __restrict__ out_scores,
                                                  float* __restrict__ out_keep,
                                                  float* __restrict__ out_ovr) {
  const int tid = threadIdx.x;
  if (blockIdx.x == NB) { // loss finalize
    if (tid < 64) {
      double acc[7] = {0,0,0,0,0,0,0};
      for (int i = tid; i < 2*BLK_PER_BATCH; i += 64) {
        const float* p = partials + i*5;
        acc[0] += p[0]; acc[1] += p[1]; acc[2] += p[3];
        if (i < BLK_PER_BATCH) { acc[3] += p[2]; acc[5] += p[4]; }
        else                   { acc[4] += p[2]; acc[6] += p[4]; }
      }
      #pragma unroll
      for (int k = 0; k < 7; ++k)
        for (int off = 32; off; off >>= 1)
          acc[k] += __shfl_down(acc[k], off);
      if (tid == 0) {
        double posg = acc[3] + acc[4];
        double cls_pos = acc[0] / (posg + 1e-6);
        double cls_neg = acc[1] / (acc[2] + 1e-6);
        double loss_prob = 1.5*cls_pos + cls_neg;
        double ps0 = fmax(acc[3], 1.0), ps1 = fmax(acc[4], 1.0);
        double loss_reg = (acc[5]/ps0 + acc[6]/ps1) / (double)NB;
        out_loss[0] = (float)(loss_prob + loss_reg);
      }
    }
    return;
  }
  const int b = blockIdx.x;
  __shared__ unsigned sA[NBIN], sB[NBIN];
  __shared__ unsigned long long comp[CANDCAP];
  __shared__ int sT1, sCnt;

  // threshold from histogram
  suffix2048(hist1 + b*NBIN, sA, sB);
  for (int i = tid; i < NBIN; i += 1024)
    if (sA[i] >= (unsigned)KP && (i == NBIN-1 || sA[i+1] < (unsigned)KP)) sT1 = i;
  if (tid == 0) sCnt = 0;
  __syncthreads();
  const unsigned T1 = (unsigned)sT1;

  // collect candidates from own batch's pobj (L2/L3-resident)
  const float4* v4 = (const float4*)(pobj + (size_t)b*MVOX);
  for (int i4 = tid; i4 < MVOX/4; i4 += 1024) {
    float4 f = v4[i4];
    unsigned kk[4] = {__float_as_uint(f.x), __float_as_uint(f.y),
                      __float_as_uint(f.z), __float_as_uint(f.w)};
    #pragma unroll
    for (int j = 0; j < 4; ++j) {
      const unsigned k = kk[j];
      if (pjbin(k) >= T1) {
        int p = atomicAdd(&sCnt, 1);
        if (p < CANDCAP)
          comp[p] = ((unsigned long long)(~k) << 32) | (unsigned)(i4*4 + j);
      }
    }
  }
  __syncthreads();
  const int n = min(sCnt, CANDCAP);
  int P = 256; while (P < n) P <<= 1;
  for (int i = n + tid; i < P; i += 1024) comp[i] = ~0ull;
  __syncthreads();
  for (int k = 2; k <= P; k <<= 1)
    for (int jj = k >> 1; jj > 0; jj >>= 1) {
      for (int i = tid; i < P; i += 1024) {
        const int ixj = i ^ jj;
        if (ixj > i) {
          unsigned long long aa = comp[i], cc = comp[ixj];
          bool up = ((i & k) == 0);
          if ((aa > cc) == up) { comp[i] = cc; comp[ixj] = aa; }
        }
      }
      __syncthreads();
    }

  __shared__ float Bxy[KP][4], Bzx[KP][4];
  __shared__ unsigned long long RowXY[KP][2], RowZX[KP][2];
  __shared__ unsigned long long keepS[2];
  __shared__ unsigned char validArr[KP];
  __shared__ float Gmin[NGT][3], Gmax[NGT][3], Gvol[NGT], Gsc[NGT];

  const int j = tid;
  float val = 0.f, cx=0,cy=0,cz=0,bm0=0,bm1=0,bm2=0,bM0=0,bM1=0,bM2=0;
  if (j < KP) {
    const unsigned long long cc = comp[j];
    val = __uint_as_float(~(unsigned)(cc >> 32));
    const int idx = (int)(cc & 0xffffffffull);
    const int xi = idx / (YD*ZD), yi = (idx / ZD) % YD, zi = idx % ZD;
    const size_t zmaj = (size_t)zi*(YD*XD) + yi*XD + xi;
    float dl[6];
    #pragma unroll
    for (int c = 0; c < 6; ++c) dl[c] = cbias[1 + c];
    for (int g = 0; g < G; ++g) {
      const float* p = pred4 + ((size_t)(g*NB + b)*7)*MVOX + zmaj;
      #pragma unroll
      for (int c = 0; c < 6; ++c) dl[c] += p[(size_t)(1 + c)*MVOX];
    }
    cx = (float)xi + dl[0]*ANCH; cy = (float)yi + dl[1]*ANCH; cz = (float)zi + dl[2]*ANCH;
    float hx = 0.5f*expf(dl[3])*ANCH, hy = 0.5f*expf(dl[4])*ANCH, hz = 0.5f*expf(dl[5])*ANCH;
    bm0 = cx - hx; bm1 = cy - hy; bm2 = cz - hz;
    bM0 = cx + hx; bM1 = cy + hy; bM2 = cz + hz;
    const bool valid = val > 0.9f;
    validArr[j] = valid ? 1 : 0;
    float vm0 = valid ? bm0 : 0.f, vm1 = valid ? bm1 : 0.f, vm2 = valid ? bm2 : 0.f;
    float vM0 = valid ? bM0 : 0.f, vM1 = valid ? bM1 : 0.f, vM2 = valid ? bM2 : 0.f;
    Bxy[j][0] = vm1; Bxy[j][1] = vm2; Bxy[j][2] = vM1; Bxy[j][3] = vM2;
    Bzx[j][0] = vm0; Bzx[j][1] = vm2; Bzx[j][2] = vM0; Bzx[j][3] = vM2;
  }
  if (j >= KP && j < KP + NGT) {
    const int jn = j - KP;
    const float* g = lrt + (b*NGT + jn)*19;
    float l0 = g[0], l1 = g[1], l2 = g[2];
    float R00=g[3],R01=g[4],R02=g[5],  t0=g[6];
    float R10=g[7],R11=g[8],R12=g[9],  t1=g[10];
    float R20=g[11],R21=g[12],R22=g[13],t2=g[14];
    float mn0=1e30f,mn1=1e30f,mn2=1e30f,mx0=-1e30f,mx1=-1e30f,mx2=-1e30f;
    #pragma unroll
    for (int s = 0; s < 8; ++s) {
      float sx = (s & 4) ? 0.5f : -0.5f;
      float sy = (s & 2) ? 0.5f : -0.5f;
      float sz = (s & 1) ? 0.5f : -0.5f;
      float px = sx*l0, py = sy*l1, pz = sz*l2;
      float c0 = R00*px + R01*py + R02*pz + t0;
      float c1 = R10*px + R11*py + R12*pz + t1;
      float c2 = R20*px + R21*py + R22*pz + t2;
      mn0 = fminf(mn0, c0); mx0 = fmaxf(mx0, c0);
      mn1 = fminf(mn1, c1); mx1 = fmaxf(mx1, c1);
      mn2 = fminf(mn2, c2); mx2 = fmaxf(mx2, c2);
    }
    Gmin[jn][0]=mn0; Gmin[jn][1]=mn1; Gmin[jn][2]=mn2;
    Gmax[jn][0]=mx0; Gmax[jn][1]=mx1; Gmax[jn][2]=mx2;
    Gvol[jn] = (mx0-mn0)*(mx1-mn1)*(mx2-mn2);
    Gsc[jn] = (scores[b*NGT + jn] > 0.f) ? 1.f : 0.f;
  }
  __syncthreads();

  if (j < KP) {
    unsigned long long rx0=0, rx1=0, rz0=0, rz1=0;
    for (int i = 0; i < KP; ++i) {
      bool bx_ = iou2(Bxy[j], Bxy[i]) > 0.2f;
      bool bz_ = iou2(Bzx[j], Bzx[i]) > 0.2f;
      if (i < 64) { if (bx_) rx0 |= 1ull << i;      if (bz_) rz0 |= 1ull << i; }
      else        { if (bx_) rx1 |= 1ull << (i-64); if (bz_) rz1 |= 1ull << (i-64); }
    }
    RowXY[j][0]=rx0; RowXY[j][1]=rx1; RowZX[j][0]=rz0; RowZX[j][1]=rz1;
  }
  __syncthreads();

  if (j == 0) {
    unsigned long long kx0=0,kx1=0,kz0=0,kz1=0;
    for (int i = 0; i < KP; ++i) {
      unsigned long long m0, m1;
      if (i < 64) { m0 = (i==0) ? 0ull : ((1ull<<i)-1ull); m1 = 0ull; }
      else        { m0 = ~0ull; m1 = (i==64) ? 0ull : ((1ull<<(i-64))-1ull); }
      bool supx = ((RowXY[i][0] & kx0 & m0) | (RowXY[i][1] & kx1 & m1)) != 0ull;
      bool supz = ((RowZX[i][0] & kz0 & m0) | (RowZX[i][1] & kz1 & m1)) != 0ull;
      bool vv = validArr[i] != 0;
      if (vv && !supx) { if (i<64) kx0 |= 1ull<<i; else kx1 |= 1ull<<(i-64); }
      if (vv && !supz) { if (i<64) kz0 |= 1ull<<i; else kz1 |= 1ull<<(i-64); }
    }
    keepS[0] = kx0 | kz0; keepS[1] = kx1 | kz1;
  }
  __syncthreads();

  if (j < KP) {
    const bool keep = (j < 64) ? ((keepS[0] >> j) & 1ull) : ((keepS[1] >> (j-64)) & 1ull);
    const float kf = keep ? 1.f : 0.f;
    float* ob = out_boxes + ((size_t)b*KP + j)*6;
    ob[0] = cx*kf; ob[1] = cy*kf; ob[2] = cz*kf;
    ob[3] = (bM0-bm0)*kf; ob[4] = (bM1-bm1)*kf; ob[5] = (bM2-bm2)*kf;
    out_scores[b*KP + j] = val * kf;
    out_keep[b*KP + j] = kf;
    const float volA = (bM0-bm0)*(bM1-bm1)*(bM2-bm2);
    for (int n2 = 0; n2 < NGT; ++n2) {
      float lo0 = fmaxf(bm0, Gmin[n2][0]), lo1 = fmaxf(bm1, Gmin[n2][1]), lo2 = fmaxf(bm2, Gmin[n2][2]);
      float hi0 = fminf(bM0, Gmax[n2][0]), hi1 = fminf(bM1, Gmax[n2][1]), hi2 = fminf(bM2, Gmax[n2][2]);
      float inter = fmaxf(hi0-lo0, 0.f)*fmaxf(hi1-lo1, 0.f)*fmaxf(hi2-lo2, 0.f);
      float iou3 = inter / (volA + Gvol[n2] - inter + 1e-9f);
      out_ovr[((size_t)b*KP + j)*NGT + n2] = iou3 * kf * Gsc[n2];
    }
  }
}

extern "C" void kernel_launch(void* const* d_in, const int* in_sizes, int n_in,
                              void* d_out, int out_size, void* d_ws, size_t ws_size,
                              hipStream_t stream) {
  const float* lrt    = (const float*)d_in[0];
  const float* scores = (const float*)d_in[1];
  const float* feat   = (const float*)d_in[2];
  const float* Wt     = (const float*)d_in[3];
  const float* cbias  = (const float*)d_in[4];

  float* out = (float*)d_out;
  float* out_loss   = out;
  float* out_pobj   = out + 1;
  float* out_boxes  = out_pobj + NB*MVOX;
  float* out_scores = out_boxes + NB*KP*6;
  float* out_keep   = out_scores + NB*KP;
  float* out_ovr    = out_keep + NB*KP;

  const size_t per = (size_t)NB*MVOX*7; // floats per channel-group
  const size_t tail_f = NB*NBIN + 2*BLK_PER_BATCH*5 + 64;
  int G = 8;
  while (G > 1 && ws_size < (per*(size_t)G + tail_f)*sizeof(float)) G >>= 1;

  float*    pred4    = (float*)d_ws;                       // G*per
  unsigned* hist1    = (unsigned*)(pred4 + per*(size_t)G); // NB*NBIN
  float*    partials = (float*)(hist1 + NB*NBIN);          // 2*432*5
  const int zeroN = NB*NBIN;

  dim3 cgrid(ZD, 2, NB*G);
  dim3 cblk(192);
  if (G == 8) {
    conv_kernel<8><<<cgrid, cblk, 0, stream>>>(feat, Wt, pred4, hist1, zeroN);
    loss_kernel<8><<<dim3(2*BLK_PER_BATCH), dim3(256), 0, stream>>>(pred4, cbias, lrt, scores,
                                                                    out_pobj, partials, hist1);
  } else if (G == 4) {
    conv_kernel<16><<<cgrid, cblk, 0, stream>>>(feat, Wt, pred4, hist1, zeroN);
    loss_kernel<4><<<dim3(2*BLK_PER_BATCH), dim3(256), 0, stream>>>(pred4, cbias, lrt, scores,
                                                                    out_pobj, partials, hist1);
  } else if (G == 2) {
    conv_kernel<32><<<cgrid, cblk, 0, stream>>>(feat, Wt, pred4, hist1, zeroN);
    loss_kernel<2><<<dim3(2*BLK_PER_BATCH), dim3(256), 0, stream>>>(pred4, cbias, lrt, scores,
                                                                    out_pobj, partials, hist1);
  } else {
    conv_kernel<64><<<cgrid, cblk, 0, stream>>>(feat, Wt, pred4, hist1, zeroN);
    loss_kernel<1><<<dim3(2*BLK_PER_BATCH), dim3(256), 0, stream>>>(pred4, cbias, lrt, scores,
                                                                    out_pobj, partials, hist1);
  }
  final_all<<<dim3(NB + 1), dim3(1024), 0, stream>>>(out_pobj, hist1, pred4, cbias, G,
                                                     lrt, scores, partials, out_loss,
                                                     out_boxes, out_scores, out_keep, out_ovr);
}

// Round 15
// 181.924 us; speedup vs baseline: 1.1038x; 1.1038x over previous
//
#include <hip/hip_runtime.h>
#include <math.h>

#define XD 48
#define YD 48
#define ZD 48
#define CD 64
#define NGT 10
#define NB 2
#define KP 128
#define MVOX (XD*YD*ZD)   // 110592
#define ANCH 12.0f
#define BLK_PER_BATCH 432 // MVOX/256

// topk: single-level log-distance histogram select
#define NBIN 2048
#define CANDCAP 4096

typedef float v2f __attribute__((ext_vector_type(2)));

// bin' (inverted: larger bin' = larger pj), monotone in pj bits. Exact superset filter.
__device__ __forceinline__ unsigned pjbin(unsigned pbits) {
  unsigned d = 0x3F800000u - pbits;         // ULP-distance from 1.0 (pj in [0,1])
  if (d == 0u) return 2047u;
  int msb = 31 - __clz(d);
  unsigned frac = (msb >= 6) ? ((d >> (msb - 6)) & 63u) : ((d << (6 - msb)) & 63u);
  unsigned bin = ((unsigned)msb << 6) | frac; // monotone increasing in d, < 1920
  return 2047u - bin;                         // invert: suffix-scan finds top
}

// ---------------- conv: direct, x-strips of 6, shfl halos, packed f32 FMA (R11/R13 body) ----------------
// pred4 layout (z-major): pred4[((cg*NB+b)*7+o)*MVOX + z*(YD*XD) + y*XD + x]
template<int CPG>
__global__ __launch_bounds__(192) void conv_kernel(const float* __restrict__ feat_zyx,
                                                   const float* __restrict__ Wt,
                                                   float* __restrict__ pred4,
                                                   unsigned* __restrict__ zeroBuf,
                                                   int zeroN) {
  const int t = threadIdx.x;
  const int q = t & 7;                 // x-segment 0..7 (x0 = 6q)
  const int y = blockIdx.y*24 + (t >> 3);
  const int z = blockIdx.x;
  const int cg = blockIdx.z >> 1;      // NB == 2
  const int b  = blockIdx.z & 1;
  const int c0 = cg * CPG;
  const int x0 = q * 6;

  // fused zeroing of topk histogram/counters (conv completes before loss)
  if (blockIdx.x == 0 && blockIdx.y == 0 && blockIdx.z == 0)
    for (int i = t; i < zeroN; i += 192) zeroBuf[i] = 0u;

  v2f acc[7][3];
  #pragma unroll
  for (int o = 0; o < 7; ++o)
    #pragma unroll
    for (int j = 0; j < 3; ++j) acc[o][j] = (v2f){0.f, 0.f};

  const float* fb = feat_zyx + ((size_t)b*CD + c0) * MVOX;
  for (int cc = 0; cc < CPG; ++cc) {
    const float* fc = fb + (size_t)cc * MVOX;
    const float* Wc = Wt + (c0 + cc) * 27;
    #pragma unroll
    for (int dz = -1; dz <= 1; ++dz) {
      const int zz = z + dz;
      if (zz < 0 || zz >= ZD) continue;      // wave-uniform (z per block)
      #pragma unroll
      for (int dy = -1; dy <= 1; ++dy) {
        const int yy = y + dy;
        const bool vrow = (yy >= 0 && yy < YD);
        const float* rp = fc + (zz*YD + (vrow ? yy : 0))*XD + x0; // 8B-aligned, in-bounds
        float2 p01 = *(const float2*)(rp);
        float2 p23 = *(const float2*)(rp + 2);
        float2 p45 = *(const float2*)(rp + 4);
        const float e1 = vrow ? p01.x : 0.f, e2 = vrow ? p01.y : 0.f;
        const float e3 = vrow ? p23.x : 0.f, e4 = vrow ? p23.y : 0.f;
        const float e5 = vrow ? p45.x : 0.f, e6 = vrow ? p45.y : 0.f;
        const float eL = __shfl_up(e6, 1);   // lane q-1 (same y-group), masked at q==0
        const float eR = __shfl_down(e1, 1); // lane q+1, masked at q==7
        const float e0 = (q == 0) ? 0.f : eL;
        const float e7 = (q == 7) ? 0.f : eR;
        const v2f A0 = {e0, e1}, A1 = {e2, e3}, A2 = {e4, e5};
        const v2f B0 = {e1, e2}, B1 = {e3, e4}, B2 = {e5, e6};
        const v2f C2 = {e6, e7};
        const int kb = (dy + 1)*3 + (dz + 1); // W[o][c][kt][dy+1][dz+1]
        #pragma unroll
        for (int o = 0; o < 7; ++o) {
          const float w0 = Wc[o*(CD*27) + kb];
          const float w1 = Wc[o*(CD*27) + 9 + kb];
          const float w2 = Wc[o*(CD*27) + 18 + kb];
          const v2f w0v = {w0, w0}, w1v = {w1, w1}, w2v = {w2, w2};
          acc[o][0] = __builtin_elementwise_fma(A0, w0v, acc[o][0]);
          acc[o][0] = __builtin_elementwise_fma(B0, w1v, acc[o][0]);
          acc[o][0] = __builtin_elementwise_fma(A1, w2v, acc[o][0]);
          acc[o][1] = __builtin_elementwise_fma(A1, w0v, acc[o][1]);
          acc[o][1] = __builtin_elementwise_fma(B1, w1v, acc[o][1]);
          acc[o][1] = __builtin_elementwise_fma(A2, w2v, acc[o][1]);
          acc[o][2] = __builtin_elementwise_fma(A2, w0v, acc[o][2]);
          acc[o][2] = __builtin_elementwise_fma(B2, w1v, acc[o][2]);
          acc[o][2] = __builtin_elementwise_fma(C2, w2v, acc[o][2]);
        }
      }
    }
  }
  float* pb = pred4 + ((size_t)(cg*NB + b)*7)*MVOX + (size_t)z*(YD*XD) + y*XD + x0;
  #pragma unroll
  for (int o = 0; o < 7; ++o) {
    *(v2f*)(pb + (size_t)o*MVOX)     = acc[o][0];
    *(v2f*)(pb + (size_t)o*MVOX + 2) = acc[o][1];
    *(v2f*)(pb + (size_t)o*MVOX + 4) = acc[o][2];
  }
}

// ---------------- loss + fused log-bin histogram (z-major iteration) ----------------
template<int GG>
__global__ __launch_bounds__(256) void loss_kernel(const float* __restrict__ pred4,
                                                   const float* __restrict__ cbias,
                                                   const float* __restrict__ lrt,
                                                   const float* __restrict__ scores,
                                                   float* __restrict__ pobj,
                                                   float* __restrict__ partials,
                                                   unsigned* __restrict__ hist1) {
  const int blk = blockIdx.x;
  const int b = blk / BLK_PER_BATCH;
  const int w = (blk % BLK_PER_BATCH) * 256 + threadIdx.x; // z-major linear
  const int z = w / (YD*XD);
  const int rem = w % (YD*XD);
  const int y = rem / XD, x = rem % XD;

  __shared__ float gp[NGT][10];
  __shared__ unsigned lh[NBIN];
  for (int i = threadIdx.x; i < NBIN; i += 256) lh[i] = 0;
  if (threadIdx.x < NGT) {
    const float* g = lrt + (b*NGT + threadIdx.x)*19;
    float l0 = g[0], l1 = g[1], l2 = g[2];
    gp[threadIdx.x][0] = g[6]; gp[threadIdx.x][1] = g[10]; gp[threadIdx.x][2] = g[14];
    gp[threadIdx.x][3] = l0*0.5f + 1e-5f;
    gp[threadIdx.x][4] = l1*0.5f + 1e-5f;
    gp[threadIdx.x][5] = l2*0.5f + 1e-5f;
    gp[threadIdx.x][6] = logf(l0 / ANCH);
    gp[threadIdx.x][7] = logf(l1 / ANCH);
    gp[threadIdx.x][8] = logf(l2 / ANCH);
    gp[threadIdx.x][9] = scores[b*NGT + threadIdx.x];
  }
  __syncthreads();

  float pv[7];
  #pragma unroll
  for (int k = 0; k < 7; ++k) pv[k] = cbias[k];
  #pragma unroll
  for (int g = 0; g < GG; ++g) {
    const float* p = pred4 + ((size_t)(g*NB + b)*7)*MVOX + w;
    #pragma unroll
    for (int k = 0; k < 7; ++k) pv[k] += p[(size_t)k*MVOX];
  }

  const float l = pv[0];
  const float pj = 1.f / (1.f + expf(-l));
  pobj[(size_t)b*MVOX + x*(YD*ZD) + y*ZD + z] = pj; // x-major output order
  atomicAdd(&lh[pjbin(__float_as_uint(pj))], 1u);

  const float fx = (float)x, fy = (float)y, fz = (float)z;
  float cum = 0.f, sneg = 0.f;
  float a[6] = {0.f,0.f,0.f,0.f,0.f,0.f};
  #pragma unroll
  for (int n = 0; n < NGT; ++n) {
    float d0 = gp[n][0] - fx, d1 = gp[n][1] - fy, d2 = gp[n][2] - fz;
    float od = fmaxf(fmaxf(fabsf(d0)/gp[n][3],
                           fabsf(d1)/gp[n][4]),
                           fabsf(d2)/gp[n][5]);
    float sc = gp[n][9];
    float mp = (od < 0.5f) ? sc : 0.f;
    float mn = (od < 0.8f) ? sc : 0.f;
    float prev = (cum >= 0.5f) ? 1.f : 0.f;
    float ctb = mp * (1.f - prev);
    a[0] += ctb * (d0 / ANCH);
    a[1] += ctb * (d1 / ANCH);
    a[2] += ctb * (d2 / ANCH);
    a[3] += ctb * gp[n][6];
    a[4] += ctb * gp[n][7];
    a[5] += ctb * gp[n][8];
    cum += mp; sneg += mn;
  }
  const float pos = (cum  >= 0.5f) ? 1.f : 0.f;
  const float neg = 1.f - ((sneg >= 0.5f) ? 1.f : 0.f);
  const float bce = fmaxf(l, 0.f) - l*pos + log1pf(expf(-fabsf(l)));
  float sl = 0.f;
  #pragma unroll
  for (int c = 0; c < 6; ++c) {
    float dd = pos * pv[1+c] - pos * a[c];
    float ad = fabsf(dd);
    sl += (ad < (1.f/9.f)) ? dd*dd*4.5f : (ad - (1.f/18.f));
  }

  float vals5[5] = {bce*pos, bce*neg, pos, neg, sl};
  __shared__ float red[4][5];
  const int lane = threadIdx.x & 63, wid = threadIdx.x >> 6;
  #pragma unroll
  for (int k = 0; k < 5; ++k)
    for (int off = 32; off; off >>= 1)
      vals5[k] += __shfl_down(vals5[k], off);
  if (lane == 0) {
    #pragma unroll
    for (int k = 0; k < 5; ++k) red[wid][k] = vals5[k];
  }
  __syncthreads();
  if (threadIdx.x == 0) {
    #pragma unroll
    for (int k = 0; k < 5; ++k)
      partials[blk*5 + k] = red[0][k] + red[1][k] + red[2][k] + red[3][k];
  }
  for (int i = threadIdx.x; i < NBIN; i += 256) {
    unsigned h = lh[i];
    if (h) atomicAdd(&hist1[b*NBIN + i], h);
  }
}

// suffix scan of ghist into sA (uses sB as ping-pong), stride 256. Result in sA.
__device__ __forceinline__ void suffix2048(const unsigned* __restrict__ ghist,
                                           unsigned* sA, unsigned* sB) {
  for (int i = threadIdx.x; i < NBIN; i += 256) sA[i] = ghist[i];
  __syncthreads();
  unsigned* src = sA; unsigned* dst = sB;
  for (int off = 1; off < NBIN; off <<= 1) {
    for (int i = threadIdx.x; i < NBIN; i += 256)
      dst[i] = src[i] + ((i + off < NBIN) ? src[i + off] : 0u);
    __syncthreads();
    unsigned* t = src; src = dst; dst = t;
  }
  if (src != sA) {
    for (int i = threadIdx.x; i < NBIN; i += 256) sA[i] = src[i];
    __syncthreads();
  }
}

// ---------------- collect candidates (single level, 54xNB parallel blocks) ----------------
__global__ __launch_bounds__(256) void topk_collect(const float* __restrict__ pobj,
                                                    const unsigned* __restrict__ hist1,
                                                    unsigned* __restrict__ selCnt,
                                                    unsigned long long* __restrict__ cand) {
  const int b = blockIdx.y;
  __shared__ unsigned sA[NBIN], sB[NBIN];
  __shared__ int sT1;
  suffix2048(hist1 + b*NBIN, sA, sB);
  for (int i = threadIdx.x; i < NBIN; i += 256)
    if (sA[i] >= (unsigned)KP && (i == NBIN-1 || sA[i+1] < (unsigned)KP)) sT1 = i;
  __syncthreads();
  const unsigned T1 = (unsigned)sT1;

  const float4* v4 = (const float4*)(pobj + (size_t)b*MVOX);
  #pragma unroll
  for (int r = 0; r < 2; ++r) {
    const int i4 = blockIdx.x*512 + r*256 + threadIdx.x;
    float4 f = v4[i4];
    unsigned kk[4] = {__float_as_uint(f.x), __float_as_uint(f.y),
                      __float_as_uint(f.z), __float_as_uint(f.w)};
    #pragma unroll
    for (int j = 0; j < 4; ++j) {
      const unsigned k = kk[j];
      if (pjbin(k) >= T1) {
        unsigned p = atomicAdd(&selCnt[b], 1u);
        if (p < CANDCAP)
          cand[(size_t)b*CANDCAP + p] =
            ((unsigned long long)(~k) << 32) | (unsigned)(i4*4 + j);
      }
    }
  }
}

// ---------------- fused: final sort + NMS + outputs (+ loss finalize) ----------------
__device__ inline float iou2(const float* A, const float* Bb) {
  float lo1 = fmaxf(A[0], Bb[0]), lo2 = fmaxf(A[1], Bb[1]);
  float hi1 = fminf(A[2], Bb[2]), hi2 = fminf(A[3], Bb[3]);
  float inter = fmaxf(hi1 - lo1, 0.f) * fmaxf(hi2 - lo2, 0.f);
  float aA = (A[2]-A[0])*(A[3]-A[1]);
  float aB = (Bb[2]-Bb[0])*(Bb[3]-Bb[1]);
  return inter / (aA + aB - inter + 1e-9f);
}

__global__ __launch_bounds__(256) void final_nms(const unsigned* __restrict__ selCnt,
                                                 const unsigned long long* __restrict__ cand,
                                                 const float* __restrict__ pred4,
                                                 const float* __restrict__ cbias,
                                                 int G,
                                                 const float* __restrict__ lrt,
                                                 const float* __restrict__ scores,
                                                 const float* __restrict__ partials,
                                                 float* __restrict__ out_loss,
                                                 float* __restrict__ out_boxes,
                                                 float* __restrict__ out_scores,
                                                 float* __restrict__ out_keep,
                                                 float* __restrict__ out_ovr) {
  const int tid = threadIdx.x;
  if (blockIdx.x == NB) { // loss finalize
    if (tid < 64) {
      double acc[7] = {0,0,0,0,0,0,0};
      for (int i = tid; i < 2*BLK_PER_BATCH; i += 64) {
        const float* p = partials + i*5;
        acc[0] += p[0]; acc[1] += p[1]; acc[2] += p[3];
        if (i < BLK_PER_BATCH) { acc[3] += p[2]; acc[5] += p[4]; }
        else                   { acc[4] += p[2]; acc[6] += p[4]; }
      }
      #pragma unroll
      for (int k = 0; k < 7; ++k)
        for (int off = 32; off; off >>= 1)
          acc[k] += __shfl_down(acc[k], off);
      if (tid == 0) {
        double posg = acc[3] + acc[4];
        double cls_pos = acc[0] / (posg + 1e-6);
        double cls_neg = acc[1] / (acc[2] + 1e-6);
        double loss_prob = 1.5*cls_pos + cls_neg;
        double ps0 = fmax(acc[3], 1.0), ps1 = fmax(acc[4], 1.0);
        double loss_reg = (acc[5]/ps0 + acc[6]/ps1) / (double)NB;
        out_loss[0] = (float)(loss_prob + loss_reg);
      }
    }
    return;
  }
  const int b = blockIdx.x;
  __shared__ unsigned long long comp[CANDCAP];
  const int n = min((int)selCnt[b], CANDCAP);
  int P = 256; while (P < n) P <<= 1;
  for (int i = tid; i < P; i += 256)
    comp[i] = (i < n) ? cand[(size_t)b*CANDCAP + i] : ~0ull;
  __syncthreads();
  for (int k = 2; k <= P; k <<= 1)
    for (int jj = k >> 1; jj > 0; jj >>= 1) {
      for (int i = tid; i < P; i += 256) {
        const int ixj = i ^ jj;
        if (ixj > i) {
          unsigned long long aa = comp[i], cc = comp[ixj];
          bool up = ((i & k) == 0);
          if ((aa > cc) == up) { comp[i] = cc; comp[ixj] = aa; }
        }
      }
      __syncthreads();
    }

  __shared__ float Bxy[KP][4], Bzx[KP][4];
  __shared__ unsigned long long RowXY[KP][2], RowZX[KP][2];
  __shared__ unsigned long long keepS[2];
  __shared__ unsigned char validArr[KP];
  __shared__ float Gmin[NGT][3], Gmax[NGT][3], Gvol[NGT], Gsc[NGT];

  const int j = tid;
  float val = 0.f, cx=0,cy=0,cz=0,bm0=0,bm1=0,bm2=0,bM0=0,bM1=0,bM2=0;
  if (j < KP) {
    const unsigned long long cc = comp[j];
    val = __uint_as_float(~(unsigned)(cc >> 32));
    const int idx = (int)(cc & 0xffffffffull);
    const int xi = idx / (YD*ZD), yi = (idx / ZD) % YD, zi = idx % ZD;
    const size_t zmaj = (size_t)zi*(YD*XD) + yi*XD + xi;
    float dl[6];
    #pragma unroll
    for (int c = 0; c < 6; ++c) dl[c] = cbias[1 + c];
    for (int g = 0; g < G; ++g) {
      const float* p = pred4 + ((size_t)(g*NB + b)*7)*MVOX + zmaj;
      #pragma unroll
      for (int c = 0; c < 6; ++c) dl[c] += p[(size_t)(1 + c)*MVOX];
    }
    cx = (float)xi + dl[0]*ANCH; cy = (float)yi + dl[1]*ANCH; cz = (float)zi + dl[2]*ANCH;
    float hx = 0.5f*expf(dl[3])*ANCH, hy = 0.5f*expf(dl[4])*ANCH, hz = 0.5f*expf(dl[5])*ANCH;
    bm0 = cx - hx; bm1 = cy - hy; bm2 = cz - hz;
    bM0 = cx + hx; bM1 = cy + hy; bM2 = cz + hz;
    const bool valid = val > 0.9f;
    validArr[j] = valid ? 1 : 0;
    float vm0 = valid ? bm0 : 0.f, vm1 = valid ? bm1 : 0.f, vm2 = valid ? bm2 : 0.f;
    float vM0 = valid ? bM0 : 0.f, vM1 = valid ? bM1 : 0.f, vM2 = valid ? bM2 : 0.f;
    Bxy[j][0] = vm1; Bxy[j][1] = vm2; Bxy[j][2] = vM1; Bxy[j][3] = vM2;
    Bzx[j][0] = vm0; Bzx[j][1] = vm2; Bzx[j][2] = vM0; Bzx[j][3] = vM2;
  }
  if (j >= KP && j < KP + NGT) {
    const int jn = j - KP;
    const float* g = lrt + (b*NGT + jn)*19;
    float l0 = g[0], l1 = g[1], l2 = g[2];
    float R00=g[3],R01=g[4],R02=g[5],  t0=g[6];
    float R10=g[7],R11=g[8],R12=g[9],  t1=g[10];
    float R20=g[11],R21=g[12],R22=g[13],t2=g[14];
    float mn0=1e30f,mn1=1e30f,mn2=1e30f,mx0=-1e30f,mx1=-1e30f,mx2=-1e30f;
    #pragma unroll
    for (int s = 0; s < 8; ++s) {
      float sx = (s & 4) ? 0.5f : -0.5f;
      float sy = (s & 2) ? 0.5f : -0.5f;
      float sz = (s & 1) ? 0.5f : -0.5f;
      float px = sx*l0, py = sy*l1, pz = sz*l2;
      float c0 = R00*px + R01*py + R02*pz + t0;
      float c1 = R10*px + R11*py + R12*pz + t1;
      float c2 = R20*px + R21*py + R22*pz + t2;
      mn0 = fminf(mn0, c0); mx0 = fmaxf(mx0, c0);
      mn1 = fminf(mn1, c1); mx1 = fmaxf(mx1, c1);
      mn2 = fminf(mn2, c2); mx2 = fmaxf(mx2, c2);
    }
    Gmin[jn][0]=mn0; Gmin[jn][1]=mn1; Gmin[jn][2]=mn2;
    Gmax[jn][0]=mx0; Gmax[jn][1]=mx1; Gmax[jn][2]=mx2;
    Gvol[jn] = (mx0-mn0)*(mx1-mn1)*(mx2-mn2);
    Gsc[jn] = (scores[b*NGT + jn] > 0.f) ? 1.f : 0.f;
  }
  __syncthreads();

  if (j < KP) {
    unsigned long long rx0=0, rx1=0, rz0=0, rz1=0;
    for (int i = 0; i < KP; ++i) {
      bool bx_ = iou2(Bxy[j], Bxy[i]) > 0.2f;
      bool bz_ = iou2(Bzx[j], Bzx[i]) > 0.2f;
      if (i < 64) { if (bx_) rx0 |= 1ull << i;      if (bz_) rz0 |= 1ull << i; }
      else        { if (bx_) rx1 |= 1ull << (i-64); if (bz_) rz1 |= 1ull << (i-64); }
    }
    RowXY[j][0]=rx0; RowXY[j][1]=rx1; RowZX[j][0]=rz0; RowZX[j][1]=rz1;
  }
  __syncthreads();

  if (j == 0) {
    unsigned long long kx0=0,kx1=0,kz0=0,kz1=0;
    for (int i = 0; i < KP; ++i) {
      unsigned long long m0, m1;
      if (i < 64) { m0 = (i==0) ? 0ull : ((1ull<<i)-1ull); m1 = 0ull; }
      else        { m0 = ~0ull; m1 = (i==64) ? 0ull : ((1ull<<(i-64))-1ull); }
      bool supx = ((RowXY[i][0] & kx0 & m0) | (RowXY[i][1] & kx1 & m1)) != 0ull;
      bool supz = ((RowZX[i][0] & kz0 & m0) | (RowZX[i][1] & kz1 & m1)) != 0ull;
      bool vv = validArr[i] != 0;
      if (vv && !supx) { if (i<64) kx0 |= 1ull<<i; else kx1 |= 1ull<<(i-64); }
      if (vv && !supz) { if (i<64) kz0 |= 1ull<<i; else kz1 |= 1ull<<(i-64); }
    }
    keepS[0] = kx0 | kz0; keepS[1] = kx1 | kz1;
  }
  __syncthreads();

  if (j < KP) {
    const bool keep = (j < 64) ? ((keepS[0] >> j) & 1ull) : ((keepS[1] >> (j-64)) & 1ull);
    const float kf = keep ? 1.f : 0.f;
    float* ob = out_boxes + ((size_t)b*KP + j)*6;
    ob[0] = cx*kf; ob[1] = cy*kf; ob[2] = cz*kf;
    ob[3] = (bM0-bm0)*kf; ob[4] = (bM1-bm1)*kf; ob[5] = (bM2-bm2)*kf;
    out_scores[b*KP + j] = val * kf;
    out_keep[b*KP + j] = kf;
    const float volA = (bM0-bm0)*(bM1-bm1)*(bM2-bm2);
    for (int n2 = 0; n2 < NGT; ++n2) {
      float lo0 = fmaxf(bm0, Gmin[n2][0]), lo1 = fmaxf(bm1, Gmin[n2][1]), lo2 = fmaxf(bm2, Gmin[n2][2]);
      float hi0 = fminf(bM0, Gmax[n2][0]), hi1 = fminf(bM1, Gmax[n2][1]), hi2 = fminf(bM2, Gmax[n2][2]);
      float inter = fmaxf(hi0-lo0, 0.f)*fmaxf(hi1-lo1, 0.f)*fmaxf(hi2-lo2, 0.f);
      float iou3 = inter / (volA + Gvol[n2] - inter + 1e-9f);
      out_ovr[((size_t)b*KP + j)*NGT + n2] = iou3 * kf * Gsc[n2];
    }
  }
}

extern "C" void kernel_launch(void* const* d_in, const int* in_sizes, int n_in,
                              void* d_out, int out_size, void* d_ws, size_t ws_size,
                              hipStream_t stream) {
  const float* lrt    = (const float*)d_in[0];
  const float* scores = (const float*)d_in[1];
  const float* feat   = (const float*)d_in[2];
  const float* Wt     = (const float*)d_in[3];
  const float* cbias  = (const float*)d_in[4];

  float* out = (float*)d_out;
  float* out_loss   = out;
  float* out_pobj   = out + 1;
  float* out_boxes  = out_pobj + NB*MVOX;
  float* out_scores = out_boxes + NB*KP*6;
  float* out_keep   = out_scores + NB*KP;
  float* out_ovr    = out_keep + NB*KP;

  const size_t per = (size_t)NB*MVOX*7; // floats per channel-group
  const size_t tail_f = 2*(size_t)NB*CANDCAP + NB*NBIN + NB + 2*BLK_PER_BATCH*5 + 64;
  int G = 8;
  while (G > 1 && ws_size < (per*(size_t)G + tail_f)*sizeof(float)) G >>= 1;

  float*              pred4    = (float*)d_ws;                                 // G*per
  unsigned long long* cand     = (unsigned long long*)(pred4 + per*(size_t)G); // NB*CANDCAP
  unsigned*           hist1    = (unsigned*)(cand + (size_t)NB*CANDCAP);       // NB*NBIN
  unsigned*           selCnt   = hist1 + NB*NBIN;                              // NB
  float*              partials = (float*)(selCnt + NB);                        // 2*432*5
  const int zeroN = NB*NBIN + NB; // hist1 + selCnt (contiguous)

  dim3 cgrid(ZD, 2, NB*G);
  dim3 cblk(192);
  if (G == 8) {
    conv_kernel<8><<<cgrid, cblk, 0, stream>>>(feat, Wt, pred4, hist1, zeroN);
    loss_kernel<8><<<dim3(2*BLK_PER_BATCH), dim3(256), 0, stream>>>(pred4, cbias, lrt, scores,
                                                                    out_pobj, partials, hist1);
  } else if (G == 4) {
    conv_kernel<16><<<cgrid, cblk, 0, stream>>>(feat, Wt, pred4, hist1, zeroN);
    loss_kernel<4><<<dim3(2*BLK_PER_BATCH), dim3(256), 0, stream>>>(pred4, cbias, lrt, scores,
                                                                    out_pobj, partials, hist1);
  } else if (G == 2) {
    conv_kernel<32><<<cgrid, cblk, 0, stream>>>(feat, Wt, pred4, hist1, zeroN);
    loss_kernel<2><<<dim3(2*BLK_PER_BATCH), dim3(256), 0, stream>>>(pred4, cbias, lrt, scores,
                                                                    out_pobj, partials, hist1);
  } else {
    conv_kernel<64><<<cgrid, cblk, 0, stream>>>(feat, Wt, pred4, hist1, zeroN);
    loss_kernel<1><<<dim3(2*BLK_PER_BATCH), dim3(256), 0, stream>>>(pred4, cbias, lrt, scores,
                                                                    out_pobj, partials, hist1);
  }
  topk_collect<<<dim3(54, NB), dim3(256), 0, stream>>>(out_pobj, hist1, selCnt, cand);
  final_nms<<<dim3(NB + 1), dim3(256), 0, stream>>>(selCnt, cand, pred4, cbias, G,
                                                    lrt, scores, partials, out_loss,
                                                    out_boxes, out_scores, out_keep, out_ovr);
}

// Round 16
// 174.595 us; speedup vs baseline: 1.1501x; 1.0420x over previous
//
#include <hip/hip_runtime.h>
#include <math.h>

#define XD 48
#define YD 48
#define ZD 48
#define CD 64
#define NGT 10
#define NB 2
#define KP 128
#define MVOX (XD*YD*ZD)   // 110592
#define ANCH 12.0f
#define BLK_PER_BATCH 432 // MVOX/256

// topk: single-level log-distance histogram select
#define NBIN 2048
#define CANDCAP 4096

typedef float v2f __attribute__((ext_vector_type(2)));

// bin' (inverted: larger bin' = larger pj), monotone in pj bits. Exact superset filter.
__device__ __forceinline__ unsigned pjbin(unsigned pbits) {
  unsigned d = 0x3F800000u - pbits;         // ULP-distance from 1.0 (pj in [0,1])
  if (d == 0u) return 2047u;
  int msb = 31 - __clz(d);
  unsigned frac = (msb >= 6) ? ((d >> (msb - 6)) & 63u) : ((d << (6 - msb)) & 63u);
  unsigned bin = ((unsigned)msb << 6) | frac; // monotone increasing in d, < 1920
  return 2047u - bin;                         // invert: suffix-scan finds top
}

// ---------------- conv: direct, x-strips of 6, shfl halos, packed f32 FMA (R11/R13 body) ----------------
// pred4 layout (z-major): pred4[((cg*NB+b)*7+o)*MVOX + z*(YD*XD) + y*XD + x]
template<int CPG>
__global__ __launch_bounds__(192) void conv_kernel(const float* __restrict__ feat_zyx,
                                                   const float* __restrict__ Wt,
                                                   float* __restrict__ pred4,
                                                   unsigned* __restrict__ zeroBuf,
                                                   int zeroN) {
  const int t = threadIdx.x;
  const int q = t & 7;                 // x-segment 0..7 (x0 = 6q)
  const int y = blockIdx.y*24 + (t >> 3);
  const int z = blockIdx.x;
  const int cg = blockIdx.z >> 1;      // NB == 2
  const int b  = blockIdx.z & 1;
  const int c0 = cg * CPG;
  const int x0 = q * 6;

  // fused zeroing of topk histogram/counters (conv completes before loss)
  if (blockIdx.x == 0 && blockIdx.y == 0 && blockIdx.z == 0)
    for (int i = t; i < zeroN; i += 192) zeroBuf[i] = 0u;

  v2f acc[7][3];
  #pragma unroll
  for (int o = 0; o < 7; ++o)
    #pragma unroll
    for (int j = 0; j < 3; ++j) acc[o][j] = (v2f){0.f, 0.f};

  const float* fb = feat_zyx + ((size_t)b*CD + c0) * MVOX;
  for (int cc = 0; cc < CPG; ++cc) {
    const float* fc = fb + (size_t)cc * MVOX;
    const float* Wc = Wt + (c0 + cc) * 27;
    #pragma unroll
    for (int dz = -1; dz <= 1; ++dz) {
      const int zz = z + dz;
      if (zz < 0 || zz >= ZD) continue;      // wave-uniform (z per block)
      #pragma unroll
      for (int dy = -1; dy <= 1; ++dy) {
        const int yy = y + dy;
        const bool vrow = (yy >= 0 && yy < YD);
        const float* rp = fc + (zz*YD + (vrow ? yy : 0))*XD + x0; // 8B-aligned, in-bounds
        float2 p01 = *(const float2*)(rp);
        float2 p23 = *(const float2*)(rp + 2);
        float2 p45 = *(const float2*)(rp + 4);
        const float e1 = vrow ? p01.x : 0.f, e2 = vrow ? p01.y : 0.f;
        const float e3 = vrow ? p23.x : 0.f, e4 = vrow ? p23.y : 0.f;
        const float e5 = vrow ? p45.x : 0.f, e6 = vrow ? p45.y : 0.f;
        const float eL = __shfl_up(e6, 1);   // lane q-1 (same y-group), masked at q==0
        const float eR = __shfl_down(e1, 1); // lane q+1, masked at q==7
        const float e0 = (q == 0) ? 0.f : eL;
        const float e7 = (q == 7) ? 0.f : eR;
        const v2f A0 = {e0, e1}, A1 = {e2, e3}, A2 = {e4, e5};
        const v2f B0 = {e1, e2}, B1 = {e3, e4}, B2 = {e5, e6};
        const v2f C2 = {e6, e7};
        const int kb = (dy + 1)*3 + (dz + 1); // W[o][c][kt][dy+1][dz+1]
        #pragma unroll
        for (int o = 0; o < 7; ++o) {
          const float w0 = Wc[o*(CD*27) + kb];
          const float w1 = Wc[o*(CD*27) + 9 + kb];
          const float w2 = Wc[o*(CD*27) + 18 + kb];
          const v2f w0v = {w0, w0}, w1v = {w1, w1}, w2v = {w2, w2};
          acc[o][0] = __builtin_elementwise_fma(A0, w0v, acc[o][0]);
          acc[o][0] = __builtin_elementwise_fma(B0, w1v, acc[o][0]);
          acc[o][0] = __builtin_elementwise_fma(A1, w2v, acc[o][0]);
          acc[o][1] = __builtin_elementwise_fma(A1, w0v, acc[o][1]);
          acc[o][1] = __builtin_elementwise_fma(B1, w1v, acc[o][1]);
          acc[o][1] = __builtin_elementwise_fma(A2, w2v, acc[o][1]);
          acc[o][2] = __builtin_elementwise_fma(A2, w0v, acc[o][2]);
          acc[o][2] = __builtin_elementwise_fma(B2, w1v, acc[o][2]);
          acc[o][2] = __builtin_elementwise_fma(C2, w2v, acc[o][2]);
        }
      }
    }
  }
  float* pb = pred4 + ((size_t)(cg*NB + b)*7)*MVOX + (size_t)z*(YD*XD) + y*XD + x0;
  #pragma unroll
  for (int o = 0; o < 7; ++o) {
    *(v2f*)(pb + (size_t)o*MVOX)     = acc[o][0];
    *(v2f*)(pb + (size_t)o*MVOX + 2) = acc[o][1];
    *(v2f*)(pb + (size_t)o*MVOX + 4) = acc[o][2];
  }
}

// ---------------- loss + fused log-bin histogram (z-major iteration, lazy delta loads) ----------------
template<int GG>
__global__ __launch_bounds__(256) void loss_kernel(const float* __restrict__ pred4,
                                                   const float* __restrict__ cbias,
                                                   const float* __restrict__ lrt,
                                                   const float* __restrict__ scores,
                                                   float* __restrict__ pobj,
                                                   float* __restrict__ partials,
                                                   unsigned* __restrict__ hist1) {
  const int blk = blockIdx.x;
  const int b = blk / BLK_PER_BATCH;
  const int w = (blk % BLK_PER_BATCH) * 256 + threadIdx.x; // z-major linear
  const int z = w / (YD*XD);
  const int rem = w % (YD*XD);
  const int y = rem / XD, x = rem % XD;

  __shared__ float gp[NGT][10];
  __shared__ unsigned lh[NBIN];
  for (int i = threadIdx.x; i < NBIN; i += 256) lh[i] = 0;
  if (threadIdx.x < NGT) {
    const float* g = lrt + (b*NGT + threadIdx.x)*19;
    float l0 = g[0], l1 = g[1], l2 = g[2];
    gp[threadIdx.x][0] = g[6]; gp[threadIdx.x][1] = g[10]; gp[threadIdx.x][2] = g[14];
    gp[threadIdx.x][3] = l0*0.5f + 1e-5f;
    gp[threadIdx.x][4] = l1*0.5f + 1e-5f;
    gp[threadIdx.x][5] = l2*0.5f + 1e-5f;
    gp[threadIdx.x][6] = logf(l0 / ANCH);
    gp[threadIdx.x][7] = logf(l1 / ANCH);
    gp[threadIdx.x][8] = logf(l2 / ANCH);
    gp[threadIdx.x][9] = scores[b*NGT + threadIdx.x];
  }
  __syncthreads();

  // logit only: read G channel-0 planes (32 B/voxel vs 224 B/voxel)
  float l = cbias[0];
  #pragma unroll
  for (int g = 0; g < GG; ++g)
    l += pred4[((size_t)(g*NB + b)*7)*MVOX + w];

  const float pj = 1.f / (1.f + expf(-l));
  pobj[(size_t)b*MVOX + x*(YD*ZD) + y*ZD + z] = pj; // x-major output order
  atomicAdd(&lh[pjbin(__float_as_uint(pj))], 1u);

  const float fx = (float)x, fy = (float)y, fz = (float)z;
  float cum = 0.f, sneg = 0.f;
  float a[6] = {0.f,0.f,0.f,0.f,0.f,0.f};
  #pragma unroll
  for (int n = 0; n < NGT; ++n) {
    float d0 = gp[n][0] - fx, d1 = gp[n][1] - fy, d2 = gp[n][2] - fz;
    float od = fmaxf(fmaxf(fabsf(d0)/gp[n][3],
                           fabsf(d1)/gp[n][4]),
                           fabsf(d2)/gp[n][5]);
    float sc = gp[n][9];
    float mp = (od < 0.5f) ? sc : 0.f;
    float mn = (od < 0.8f) ? sc : 0.f;
    float prev = (cum >= 0.5f) ? 1.f : 0.f;
    float ctb = mp * (1.f - prev);
    a[0] += ctb * (d0 / ANCH);
    a[1] += ctb * (d1 / ANCH);
    a[2] += ctb * (d2 / ANCH);
    a[3] += ctb * gp[n][6];
    a[4] += ctb * gp[n][7];
    a[5] += ctb * gp[n][8];
    cum += mp; sneg += mn;
  }
  const float pos = (cum  >= 0.5f) ? 1.f : 0.f;
  const float neg = 1.f - ((sneg >= 0.5f) ? 1.f : 0.f);
  const float bce = fmaxf(l, 0.f) - l*pos + log1pf(expf(-fabsf(l)));
  float sl = 0.f;
  if (pos > 0.f) { // rare (~5%): lazily gather the 6 delta channels
    float pv[6];
    #pragma unroll
    for (int c = 0; c < 6; ++c) pv[c] = cbias[1 + c];
    #pragma unroll
    for (int g = 0; g < GG; ++g) {
      const float* p = pred4 + ((size_t)(g*NB + b)*7)*MVOX + w;
      #pragma unroll
      for (int c = 0; c < 6; ++c) pv[c] += p[(size_t)(1 + c)*MVOX];
    }
    #pragma unroll
    for (int c = 0; c < 6; ++c) {
      float dd = pos * pv[c] - pos * a[c];
      float ad = fabsf(dd);
      sl += (ad < (1.f/9.f)) ? dd*dd*4.5f : (ad - (1.f/18.f));
    }
  }

  float vals5[5] = {bce*pos, bce*neg, pos, neg, sl};
  __shared__ float red[4][5];
  const int lane = threadIdx.x & 63, wid = threadIdx.x >> 6;
  #pragma unroll
  for (int k = 0; k < 5; ++k)
    for (int off = 32; off; off >>= 1)
      vals5[k] += __shfl_down(vals5[k], off);
  if (lane == 0) {
    #pragma unroll
    for (int k = 0; k < 5; ++k) red[wid][k] = vals5[k];
  }
  __syncthreads();
  if (threadIdx.x == 0) {
    #pragma unroll
    for (int k = 0; k < 5; ++k)
      partials[blk*5 + k] = red[0][k] + red[1][k] + red[2][k] + red[3][k];
  }
  for (int i = threadIdx.x; i < NBIN; i += 256) {
    unsigned h = lh[i];
    if (h) atomicAdd(&hist1[b*NBIN + i], h);
  }
}

// suffix scan of ghist into sA (uses sB as ping-pong), stride 256. Result in sA.
__device__ __forceinline__ void suffix2048(const unsigned* __restrict__ ghist,
                                           unsigned* sA, unsigned* sB) {
  for (int i = threadIdx.x; i < NBIN; i += 256) sA[i] = ghist[i];
  __syncthreads();
  unsigned* src = sA; unsigned* dst = sB;
  for (int off = 1; off < NBIN; off <<= 1) {
    for (int i = threadIdx.x; i < NBIN; i += 256)
      dst[i] = src[i] + ((i + off < NBIN) ? src[i + off] : 0u);
    __syncthreads();
    unsigned* t = src; src = dst; dst = t;
  }
  if (src != sA) {
    for (int i = threadIdx.x; i < NBIN; i += 256) sA[i] = src[i];
    __syncthreads();
  }
}

// ---------------- collect candidates (single level, 54xNB parallel blocks) ----------------
__global__ __launch_bounds__(256) void topk_collect(const float* __restrict__ pobj,
                                                    const unsigned* __restrict__ hist1,
                                                    unsigned* __restrict__ selCnt,
                                                    unsigned long long* __restrict__ cand) {
  const int b = blockIdx.y;
  __shared__ unsigned sA[NBIN], sB[NBIN];
  __shared__ int sT1;
  suffix2048(hist1 + b*NBIN, sA, sB);
  for (int i = threadIdx.x; i < NBIN; i += 256)
    if (sA[i] >= (unsigned)KP && (i == NBIN-1 || sA[i+1] < (unsigned)KP)) sT1 = i;
  __syncthreads();
  const unsigned T1 = (unsigned)sT1;

  const float4* v4 = (const float4*)(pobj + (size_t)b*MVOX);
  #pragma unroll
  for (int r = 0; r < 2; ++r) {
    const int i4 = blockIdx.x*512 + r*256 + threadIdx.x;
    float4 f = v4[i4];
    unsigned kk[4] = {__float_as_uint(f.x), __float_as_uint(f.y),
                      __float_as_uint(f.z), __float_as_uint(f.w)};
    #pragma unroll
    for (int j = 0; j < 4; ++j) {
      const unsigned k = kk[j];
      if (pjbin(k) >= T1) {
        unsigned p = atomicAdd(&selCnt[b], 1u);
        if (p < CANDCAP)
          cand[(size_t)b*CANDCAP + p] =
            ((unsigned long long)(~k) << 32) | (unsigned)(i4*4 + j);
      }
    }
  }
}

// ---------------- fused: final sort + NMS + outputs (+ loss finalize) ----------------
__device__ inline float iou2(const float* A, const float* Bb) {
  float lo1 = fmaxf(A[0], Bb[0]), lo2 = fmaxf(A[1], Bb[1]);
  float hi1 = fminf(A[2], Bb[2]), hi2 = fminf(A[3], Bb[3]);
  float inter = fmaxf(hi1 - lo1, 0.f) * fmaxf(hi2 - lo2, 0.f);
  float aA = (A[2]-A[0])*(A[3]-A[1]);
  float aB = (Bb[2]-Bb[0])*(Bb[3]-Bb[1]);
  return inter / (aA + aB - inter + 1e-9f);
}

__global__ __launch_bounds__(256) void final_nms(const unsigned* __restrict__ selCnt,
                                                 const unsigned long long* __restrict__ cand,
                                                 const float* __restrict__ pred4,
                                                 const float* __restrict__ cbias,
                                                 int G,
                                                 const float* __restrict__ lrt,
                                                 const float* __restrict__ scores,
                                                 const float* __restrict__ partials,
                                                 float* __restrict__ out_loss,
                                                 float* __restrict__ out_boxes,
                                                 float* __restrict__ out_scores,
                                                 float* __restrict__ out_keep,
                                                 float* __restrict__ out_ovr) {
  const int tid = threadIdx.x;
  if (blockIdx.x == NB) { // loss finalize
    if (tid < 64) {
      double acc[7] = {0,0,0,0,0,0,0};
      for (int i = tid; i < 2*BLK_PER_BATCH; i += 64) {
        const float* p = partials + i*5;
        acc[0] += p[0]; acc[1] += p[1]; acc[2] += p[3];
        if (i < BLK_PER_BATCH) { acc[3] += p[2]; acc[5] += p[4]; }
        else                   { acc[4] += p[2]; acc[6] += p[4]; }
      }
      #pragma unroll
      for (int k = 0; k < 7; ++k)
        for (int off = 32; off; off >>= 1)
          acc[k] += __shfl_down(acc[k], off);
      if (tid == 0) {
        double posg = acc[3] + acc[4];
        double cls_pos = acc[0] / (posg + 1e-6);
        double cls_neg = acc[1] / (acc[2] + 1e-6);
        double loss_prob = 1.5*cls_pos + cls_neg;
        double ps0 = fmax(acc[3], 1.0), ps1 = fmax(acc[4], 1.0);
        double loss_reg = (acc[5]/ps0 + acc[6]/ps1) / (double)NB;
        out_loss[0] = (float)(loss_prob + loss_reg);
      }
    }
    return;
  }
  const int b = blockIdx.x;
  __shared__ unsigned long long comp[CANDCAP];
  const int n = min((int)selCnt[b], CANDCAP);
  int P = 256; while (P < n) P <<= 1;
  for (int i = tid; i < P; i += 256)
    comp[i] = (i < n) ? cand[(size_t)b*CANDCAP + i] : ~0ull;
  __syncthreads();
  for (int k = 2; k <= P; k <<= 1)
    for (int jj = k >> 1; jj > 0; jj >>= 1) {
      for (int i = tid; i < P; i += 256) {
        const int ixj = i ^ jj;
        if (ixj > i) {
          unsigned long long aa = comp[i], cc = comp[ixj];
          bool up = ((i & k) == 0);
          if ((aa > cc) == up) { comp[i] = cc; comp[ixj] = aa; }
        }
      }
      __syncthreads();
    }

  __shared__ float Bxy[KP][4], Bzx[KP][4];
  __shared__ unsigned long long RowXY[KP][2], RowZX[KP][2];
  __shared__ unsigned long long keepS[2];
  __shared__ unsigned char validArr[KP];
  __shared__ float Gmin[NGT][3], Gmax[NGT][3], Gvol[NGT], Gsc[NGT];

  const int j = tid;
  float val = 0.f, cx=0,cy=0,cz=0,bm0=0,bm1=0,bm2=0,bM0=0,bM1=0,bM2=0;
  if (j < KP) {
    const unsigned long long cc = comp[j];
    val = __uint_as_float(~(unsigned)(cc >> 32));
    const int idx = (int)(cc & 0xffffffffull);
    const int xi = idx / (YD*ZD), yi = (idx / ZD) % YD, zi = idx % ZD;
    const size_t zmaj = (size_t)zi*(YD*XD) + yi*XD + xi;
    float dl[6];
    #pragma unroll
    for (int c = 0; c < 6; ++c) dl[c] = cbias[1 + c];
    for (int g = 0; g < G; ++g) {
      const float* p = pred4 + ((size_t)(g*NB + b)*7)*MVOX + zmaj;
      #pragma unroll
      for (int c = 0; c < 6; ++c) dl[c] += p[(size_t)(1 + c)*MVOX];
    }
    cx = (float)xi + dl[0]*ANCH; cy = (float)yi + dl[1]*ANCH; cz = (float)zi + dl[2]*ANCH;
    float hx = 0.5f*expf(dl[3])*ANCH, hy = 0.5f*expf(dl[4])*ANCH, hz = 0.5f*expf(dl[5])*ANCH;
    bm0 = cx - hx; bm1 = cy - hy; bm2 = cz - hz;
    bM0 = cx + hx; bM1 = cy + hy; bM2 = cz + hz;
    const bool valid = val > 0.9f;
    validArr[j] = valid ? 1 : 0;
    float vm0 = valid ? bm0 : 0.f, vm1 = valid ? bm1 : 0.f, vm2 = valid ? bm2 : 0.f;
    float vM0 = valid ? bM0 : 0.f, vM1 = valid ? bM1 : 0.f, vM2 = valid ? bM2 : 0.f;
    Bxy[j][0] = vm1; Bxy[j][1] = vm2; Bxy[j][2] = vM1; Bxy[j][3] = vM2;
    Bzx[j][0] = vm0; Bzx[j][1] = vm2; Bzx[j][2] = vM0; Bzx[j][3] = vM2;
  }
  if (j >= KP && j < KP + NGT) {
    const int jn = j - KP;
    const float* g = lrt + (b*NGT + jn)*19;
    float l0 = g[0], l1 = g[1], l2 = g[2];
    float R00=g[3],R01=g[4],R02=g[5],  t0=g[6];
    float R10=g[7],R11=g[8],R12=g[9],  t1=g[10];
    float R20=g[11],R21=g[12],R22=g[13],t2=g[14];
    float mn0=1e30f,mn1=1e30f,mn2=1e30f,mx0=-1e30f,mx1=-1e30f,mx2=-1e30f;
    #pragma unroll
    for (int s = 0; s < 8; ++s) {
      float sx = (s & 4) ? 0.5f : -0.5f;
      float sy = (s & 2) ? 0.5f : -0.5f;
      float sz = (s & 1) ? 0.5f : -0.5f;
      float px = sx*l0, py = sy*l1, pz = sz*l2;
      float c0 = R00*px + R01*py + R02*pz + t0;
      float c1 = R10*px + R11*py + R12*pz + t1;
      float c2 = R20*px + R21*py + R22*pz + t2;
      mn0 = fminf(mn0, c0); mx0 = fmaxf(mx0, c0);
      mn1 = fminf(mn1, c1); mx1 = fmaxf(mx1, c1);
      mn2 = fminf(mn2, c2); mx2 = fmaxf(mx2, c2);
    }
    Gmin[jn][0]=mn0; Gmin[jn][1]=mn1; Gmin[jn][2]=mn2;
    Gmax[jn][0]=mx0; Gmax[jn][1]=mx1; Gmax[jn][2]=mx2;
    Gvol[jn] = (mx0-mn0)*(mx1-mn1)*(mx2-mn2);
    Gsc[jn] = (scores[b*NGT + jn] > 0.f) ? 1.f : 0.f;
  }
  __syncthreads();

  if (j < KP) {
    unsigned long long rx0=0, rx1=0, rz0=0, rz1=0;
    for (int i = 0; i < KP; ++i) {
      bool bx_ = iou2(Bxy[j], Bxy[i]) > 0.2f;
      bool bz_ = iou2(Bzx[j], Bzx[i]) > 0.2f;
      if (i < 64) { if (bx_) rx0 |= 1ull << i;      if (bz_) rz0 |= 1ull << i; }
      else        { if (bx_) rx1 |= 1ull << (i-64); if (bz_) rz1 |= 1ull << (i-64); }
    }
    RowXY[j][0]=rx0; RowXY[j][1]=rx1; RowZX[j][0]=rz0; RowZX[j][1]=rz1;
  }
  __syncthreads();

  if (j == 0) {
    unsigned long long kx0=0,kx1=0,kz0=0,kz1=0;
    for (int i = 0; i < KP; ++i) {
      unsigned long long m0, m1;
      if (i < 64) { m0 = (i==0) ? 0ull : ((1ull<<i)-1ull); m1 = 0ull; }
      else        { m0 = ~0ull; m1 = (i==64) ? 0ull : ((1ull<<(i-64))-1ull); }
      bool supx = ((RowXY[i][0] & kx0 & m0) | (RowXY[i][1] & kx1 & m1)) != 0ull;
      bool supz = ((RowZX[i][0] & kz0 & m0) | (RowZX[i][1] & kz1 & m1)) != 0ull;
      bool vv = validArr[i] != 0;
      if (vv && !supx) { if (i<64) kx0 |= 1ull<<i; else kx1 |= 1ull<<(i-64); }
      if (vv && !supz) { if (i<64) kz0 |= 1ull<<i; else kz1 |= 1ull<<(i-64); }
    }
    keepS[0] = kx0 | kz0; keepS[1] = kx1 | kz1;
  }
  __syncthreads();

  if (j < KP) {
    const bool keep = (j < 64) ? ((keepS[0] >> j) & 1ull) : ((keepS[1] >> (j-64)) & 1ull);
    const float kf = keep ? 1.f : 0.f;
    float* ob = out_boxes + ((size_t)b*KP + j)*6;
    ob[0] = cx*kf; ob[1] = cy*kf; ob[2] = cz*kf;
    ob[3] = (bM0-bm0)*kf; ob[4] = (bM1-bm1)*kf; ob[5] = (bM2-bm2)*kf;
    out_scores[b*KP + j] = val * kf;
    out_keep[b*KP + j] = kf;
    const float volA = (bM0-bm0)*(bM1-bm1)*(bM2-bm2);
    for (int n2 = 0; n2 < NGT; ++n2) {
      float lo0 = fmaxf(bm0, Gmin[n2][0]), lo1 = fmaxf(bm1, Gmin[n2][1]), lo2 = fmaxf(bm2, Gmin[n2][2]);
      float hi0 = fminf(bM0, Gmax[n2][0]), hi1 = fminf(bM1, Gmax[n2][1]), hi2 = fminf(bM2, Gmax[n2][2]);
      float inter = fmaxf(hi0-lo0, 0.f)*fmaxf(hi1-lo1, 0.f)*fmaxf(hi2-lo2, 0.f);
      float iou3 = inter / (volA + Gvol[n2] - inter + 1e-9f);
      out_ovr[((size_t)b*KP + j)*NGT + n2] = iou3 * kf * Gsc[n2];
    }
  }
}

extern "C" void kernel_launch(void* const* d_in, const int* in_sizes, int n_in,
                              void* d_out, int out_size, void* d_ws, size_t ws_size,
                              hipStream_t stream) {
  const float* lrt    = (const float*)d_in[0];
  const float* scores = (const float*)d_in[1];
  const float* feat   = (const float*)d_in[2];
  const float* Wt     = (const float*)d_in[3];
  const float* cbias  = (const float*)d_in[4];

  float* out = (float*)d_out;
  float* out_loss   = out;
  float* out_pobj   = out + 1;
  float* out_boxes  = out_pobj + NB*MVOX;
  float* out_scores = out_boxes + NB*KP*6;
  float* out_keep   = out_scores + NB*KP;
  float* out_ovr    = out_keep + NB*KP;

  const size_t per = (size_t)NB*MVOX*7; // floats per channel-group
  const size_t tail_f = 2*(size_t)NB*CANDCAP + NB*NBIN + NB + 2*BLK_PER_BATCH*5 + 64;
  int G = 8;
  while (G > 1 && ws_size < (per*(size_t)G + tail_f)*sizeof(float)) G >>= 1;

  float*              pred4    = (float*)d_ws;                                 // G*per
  unsigned long long* cand     = (unsigned long long*)(pred4 + per*(size_t)G); // NB*CANDCAP
  unsigned*           hist1    = (unsigned*)(cand + (size_t)NB*CANDCAP);       // NB*NBIN
  unsigned*           selCnt   = hist1 + NB*NBIN;                              // NB
  float*              partials = (float*)(selCnt + NB);                        // 2*432*5
  const int zeroN = NB*NBIN + NB; // hist1 + selCnt (contiguous)

  dim3 cgrid(ZD, 2, NB*G);
  dim3 cblk(192);
  if (G == 8) {
    conv_kernel<8><<<cgrid, cblk, 0, stream>>>(feat, Wt, pred4, hist1, zeroN);
    loss_kernel<8><<<dim3(2*BLK_PER_BATCH), dim3(256), 0, stream>>>(pred4, cbias, lrt, scores,
                                                                    out_pobj, partials, hist1);
  } else if (G == 4) {
    conv_kernel<16><<<cgrid, cblk, 0, stream>>>(feat, Wt, pred4, hist1, zeroN);
    loss_kernel<4><<<dim3(2*BLK_PER_BATCH), dim3(256), 0, stream>>>(pred4, cbias, lrt, scores,
                                                                    out_pobj, partials, hist1);
  } else if (G == 2) {
    conv_kernel<32><<<cgrid, cblk, 0, stream>>>(feat, Wt, pred4, hist1, zeroN);
    loss_kernel<2><<<dim3(2*BLK_PER_BATCH), dim3(256), 0, stream>>>(pred4, cbias, lrt, scores,
                                                                    out_pobj, partials, hist1);
  } else {
    conv_kernel<64><<<cgrid, cblk, 0, stream>>>(feat, Wt, pred4, hist1, zeroN);
    loss_kernel<1><<<dim3(2*BLK_PER_BATCH), dim3(256), 0, stream>>>(pred4, cbias, lrt, scores,
                                                                    out_pobj, partials, hist1);
  }
  topk_collect<<<dim3(54, NB), dim3(256), 0, stream>>>(out_pobj, hist1, selCnt, cand);
  final_nms<<<dim3(NB + 1), dim3(256), 0, stream>>>(selCnt, cand, pred4, cbias, G,
                                                    lrt, scores, partials, out_loss,
                                                    out_boxes, out_scores, out_keep, out_ovr);
}